// Round 16
// baseline (483.718 us; speedup 1.0000x reference)
//
#include <hip/hip_runtime.h>

// HGNN layer, v16 — fp32. v15 with the Dv-emit regression fixed (count must
// increment Dv[neighbor bi], not Dv[row]). Top-192/row compacted key cache
// (14.2 MB), 3-slot select bisection, guarded full-recompute fallback.
// B=4, N=2304, C=64.

#define HB    4
#define HN    2304
#define HC    64
#define HK    11             // K_NEIGS + 1
#define HL    48
#define HW    22             // windows per dim
#define HE2   484            // 22*22 local edges
#define HE    (HN + HE2)
#define HRPB  4              // rows per block == waves per block
#define NSLOT 36             // keys per lane (2304/64)
#define HCAP  192            // top-cache entries per row (3 u64 per lane)
#define NPAIRS (HB * HK * HN)   // sum of Dv == 11*N per batch, exact

__global__ void hg16_sentinel(float* out, int n) {
    int i = blockIdx.x * 256 + threadIdx.x;
    if (i < n) out[i] = 12345.0f;
}

__global__ void hg16_init(int* Dv, int* indeg, float* bnsum, float* bnss) {
    int i = blockIdx.x * 256 + threadIdx.x;
    if (i < HB * HN) { Dv[i] = 0; indeg[i] = 0; }
    if (i < HC) { bnsum[i] = 0.f; bnss[i] = 0.f; }
}

// -------- linear h1 = x W^T + b, xsq, f32 transpose -----------------------
__global__ __launch_bounds__(64) void hg16_linear(const float* x, const float* W,
                                                  const float* bias, float* h1,
                                                  float* xsq, float* xT) {
    int row = blockIdx.x;            // 0..B*N-1
    int t = threadIdx.x;
    __shared__ float xr[HC];
    float v = x[row * HC + t];
    xr[t] = v;
    __syncthreads();
    float sq = v * v;
    #pragma unroll
    for (int o = 32; o > 0; o >>= 1) sq += __shfl_xor(sq, o);
    if (t == 0) xsq[row] = sq;
    int b = row / HN, n = row % HN;
    xT[(b * HC + t) * HN + n] = v;
    float acc = bias[t];
    #pragma unroll 8
    for (int c = 0; c < HC; c++) acc += xr[c] * W[t * HC + c];
    h1[row * HC + t] = acc;
}

// ======== pop machinery (v12-proven): fixed kk=11 in count ================
__device__ __forceinline__ unsigned hg16_wave_min_u32(unsigned v) {
    #pragma unroll
    for (int o = 32; o > 0; o >>= 1) {
        unsigned ov = __shfl_xor(v, o);
        v = ov < v ? ov : v;
    }
    return v;
}

#define HG16_INS4(q0, q1, q2, q3, x)                                     \
    {                                                                    \
        unsigned long long x_ = (x), n_;                                 \
        n_ = q0 < x_ ? q0 : x_; x_ = q0 < x_ ? x_ : q0; q0 = n_;         \
        n_ = q1 < x_ ? q1 : x_; x_ = q1 < x_ ? x_ : q1; q1 = n_;         \
        n_ = q2 < x_ ? q2 : x_; x_ = q2 < x_ ? x_ : q2; q2 = n_;         \
        if (x_ < q3) q3 = x_;                                            \
    }

#define HG16_CE(u, v)                                                    \
    { unsigned long long t_ = u < v ? u : v; v = u < v ? v : u; u = t_; }

#define HG16_BUILD()                                                               \
    {                                                                              \
        unsigned long long a0 = CINF, a1 = CINF, a2 = CINF, a3 = CINF;             \
        unsigned long long b0 = CINF, b1 = CINF, b2 = CINF, b3 = CINF;             \
        _Pragma("unroll")                                                          \
        for (int s = 0; s < NSLOT / 2; s++) {                                      \
            unsigned long long pa = ((unsigned long long)key[s] << 12) |           \
                                    (unsigned)((s << 6) | lane);                   \
            unsigned long long pb = ((unsigned long long)key[s + 18] << 12) |      \
                                    (unsigned)(((s + 18) << 6) | lane);            \
            HG16_INS4(a0, a1, a2, a3, pa);                                         \
            HG16_INS4(b0, b1, b2, b3, pb);                                         \
        }                                                                          \
        c0 = a0 < b3 ? a0 : b3; c1 = a1 < b2 ? a1 : b2;                            \
        c2 = a2 < b1 ? a2 : b1; c3 = a3 < b0 ? a3 : b0;                            \
        HG16_CE(c0, c2); HG16_CE(c1, c3); HG16_CE(c0, c1); HG16_CE(c2, c3);        \
    }

#define HG16_EXTRACT(kk, EMIT)                                                     \
    {                                                                              \
        for (int j = 0; j < (kk); j++) {                                           \
            unsigned hk = (unsigned)(c0 >> 12);                                    \
            unsigned mk = hg16_wave_min_u32(hk);                                   \
            unsigned long long bal = __ballot(hk == mk);                           \
            bool iswin;                                                            \
            if (__popcll(bal) == 1) {                                              \
                iswin = (hk == mk);                                                \
            } else {                                                               \
                unsigned mc = (hk == mk) ? (unsigned)(c0 & 0xFFFu) : 0xFFFFFFFFu;  \
                unsigned mm = hg16_wave_min_u32(mc);                               \
                iswin = (mc == mm);                                                \
            }                                                                      \
            if (iswin) {                                                           \
                int bi = (int)(c0 & 0xFFFu);                                       \
                EMIT;                                                              \
                unsigned long long popped = c0;                                    \
                c0 = c1; c1 = c2; c2 = c3; c3 = CINF;                              \
                if (c0 == CINF) {                                                  \
                    _Pragma("unroll")                                              \
                    for (int s = 0; s < NSLOT; s++) {                              \
                        unsigned long long pk =                                    \
                            ((unsigned long long)key[s] << 12) |                   \
                            (unsigned)((s << 6) | lane);                           \
                        if (pk > popped) HG16_INS4(c0, c1, c2, c3, pk);            \
                    }                                                              \
                }                                                                  \
            }                                                                      \
        }                                                                          \
    }

// ======== bisection machinery (v13-proven), templated on slot count =======
template <int NS>
__device__ __forceinline__ void hg16_kth(const unsigned (&key)[NS], int kk,
                                         unsigned& T, int& cntLess, int& take) {
    unsigned andv = 0xFFFFFFFFu, orv = 0u;
    #pragma unroll
    for (int s = 0; s < NS; s++) { andv &= key[s]; orv |= key[s]; }
    #pragma unroll
    for (int o = 32; o > 0; o >>= 1) {
        andv &= (unsigned)__shfl_xor((int)andv, o);
        orv  |= (unsigned)__shfl_xor((int)orv, o);
    }
    unsigned diff = andv ^ orv;
    if (diff == 0u) { T = andv; cntLess = 0; take = kk; return; }
    int tstart = 31 - __builtin_clz(diff);
    unsigned lowmask = (tstart == 31) ? 0xFFFFFFFFu : ((1u << (tstart + 1)) - 1u);
    unsigned pref = andv & ~lowmask;
    int r = kk;
    for (int t = tstart; t >= 0; t--) {
        unsigned pt = pref >> t;
        int c = 0;
        #pragma unroll
        for (int s = 0; s < NS; s++) c += ((key[s] >> t) == pt) ? 1 : 0;
        #pragma unroll
        for (int o = 32; o > 0; o >>= 1) c += __shfl_xor(c, o);
        if (r > c) { r -= c; pref |= (1u << t); }
    }
    T = pref; cntLess = kk - r; take = r;
}

__device__ __forceinline__ void hg16_scan64(int v, int lane, int& excl, int& total) {
    int inc = v;
    #pragma unroll
    for (int o = 1; o < 64; o <<= 1) {
        int u = __shfl_up(inc, o);
        if (lane >= o) inc += u;
    }
    excl = inc - v;
    total = __shfl(inc, 63);
}

// -------- kNN count: vec distance + pop top-11 + top-192 compact store ----
__global__ __launch_bounds__(256) void hg16_knn_count(const float* xT, const float* xsq,
                                                      int* Dv, unsigned long long* topc) {
    __shared__ float d[HRPB][HN];                // 36 KB
    __shared__ __align__(16) float xrt[HC][HRPB];
    const int t = threadIdx.x;
    const int b = blockIdx.x / (HN / HRPB);
    const int n0 = (blockIdx.x % (HN / HRPB)) * HRPB;
    const int r = t >> 6;
    const int lane = t & 63;
    xrt[lane][r] = xT[(b * HC + lane) * HN + n0 + r];
    __syncthreads();
    float xs[HRPB];
    #pragma unroll
    for (int q = 0; q < HRPB; q++) xs[q] = xsq[b * HN + n0 + q];

    #pragma unroll
    for (int i = 0; i < 4; i++) {                // m = 0..2047, float2/thread
        const int m = 512 * i + 2 * t;
        float2 d0 = {0.f, 0.f}, d1 = {0.f, 0.f}, d2 = {0.f, 0.f}, d3 = {0.f, 0.f};
        #pragma unroll 8
        for (int c = 0; c < HC; c++) {
            float4 xq = *reinterpret_cast<const float4*>(&xrt[c][0]);
            float2 xv = *reinterpret_cast<const float2*>(&xT[(b * HC + c) * HN + m]);
            d0.x += xq.x * xv.x; d0.y += xq.x * xv.y;
            d1.x += xq.y * xv.x; d1.y += xq.y * xv.y;
            d2.x += xq.z * xv.x; d2.y += xq.z * xv.y;
            d3.x += xq.w * xv.x; d3.y += xq.w * xv.y;
        }
        float s0 = xsq[b * HN + m], s1 = xsq[b * HN + m + 1];
        *reinterpret_cast<float2*>(&d[0][m]) =
            make_float2(xs[0] + s0 - 2.f * d0.x, xs[0] + s1 - 2.f * d0.y);
        *reinterpret_cast<float2*>(&d[1][m]) =
            make_float2(xs[1] + s0 - 2.f * d1.x, xs[1] + s1 - 2.f * d1.y);
        *reinterpret_cast<float2*>(&d[2][m]) =
            make_float2(xs[2] + s0 - 2.f * d2.x, xs[2] + s1 - 2.f * d2.y);
        *reinterpret_cast<float2*>(&d[3][m]) =
            make_float2(xs[3] + s0 - 2.f * d3.x, xs[3] + s1 - 2.f * d3.y);
    }
    {                                            // scalar tail m = 2048 + t
        const int m = 2048 + t;
        float d0 = 0.f, d1 = 0.f, d2 = 0.f, d3 = 0.f;
        #pragma unroll 8
        for (int c = 0; c < HC; c++) {
            float4 xq = *reinterpret_cast<const float4*>(&xrt[c][0]);
            float xv = xT[(b * HC + c) * HN + m];
            d0 += xq.x * xv; d1 += xq.y * xv; d2 += xq.z * xv; d3 += xq.w * xv;
        }
        float sm = xsq[b * HN + m];
        d[0][m] = xs[0] + sm - 2.f * d0;
        d[1][m] = xs[1] + sm - 2.f * d1;
        d[2][m] = xs[2] + sm - 2.f * d2;
        d[3][m] = xs[3] + sm - 2.f * d3;
    }
    __syncthreads();

    const int p = n0 + r;
    const int gw = b * HN + p;
    const unsigned long long CINF = ~0ull;
    unsigned int key[NSLOT];
    unsigned long long c0, c1, c2, c3;
    #pragma unroll
    for (int s = 0; s < NSLOT; s++) {
        float f = d[r][(s << 6) | lane];
        unsigned int ub = __float_as_uint(f);
        key[s] = ub ^ (((unsigned int)(((int)ub) >> 31)) | 0x80000000u);
    }
    // (a) Dv counting: pop the 11 smallest; Dv counts the POPPED NEIGHBOR
    // (v15 regression: this emitted to Dv[gw] — the row — giving uniform k=11)
    HG16_BUILD();
    HG16_EXTRACT(HK, atomicAdd(&Dv[b * HN + bi], 1));
    // (b) top-192 compact store (unsorted; covers any kk <= 192 in select)
    unsigned T; int cntLess, take;
    hg16_kth<NSLOT>(key, HCAP, T, cntLess, take);
    int cl = 0;
    #pragma unroll
    for (int s = 0; s < NSLOT; s++) cl += (key[s] < T) ? 1 : 0;
    int off, tot;
    hg16_scan64(cl, lane, off, tot);
    unsigned long long* tb = topc + (size_t)gw * HCAP;
    int w = 0;
    #pragma unroll
    for (int s = 0; s < NSLOT; s++) {
        if (key[s] < T) {
            tb[off + w] = ((unsigned long long)key[s] << 12)
                        | (unsigned)((s << 6) | lane);
            w++;
        }
    }
    int lastm = -1;
    for (int t2 = 0; t2 < take; t2++) {          // ties at T: ascending m
        int mc = 0x7FFFFFFF;
        #pragma unroll
        for (int s = 0; s < NSLOT; s++) {
            int m = (s << 6) | lane;
            if (key[s] == T && m > lastm && m < mc) mc = m;
        }
        int mmin = mc;
        #pragma unroll
        for (int o = 32; o > 0; o >>= 1) {
            int ov = __shfl_xor(mmin, o);
            mmin = ov < mmin ? ov : mmin;
        }
        if (mc == mmin)
            tb[cntLess + t2] = ((unsigned long long)T << 12) | (unsigned)mmin;
        lastm = mmin;
    }
}

// -------- exclusive scan of Dv (9216 = 256*36) into offs ------------------
__global__ __launch_bounds__(256) void hg16_scan(const int* Dv, int* offs) {
    __shared__ int part[256];
    int t = threadIdx.x;
    int base = t * 36;
    int s = 0;
    for (int i = 0; i < 36; i++) s += max(Dv[base + i], 1);
    part[t] = s;
    __syncthreads();
    if (t == 0) { int acc = 0; for (int i = 0; i < 256; i++) { int v = part[i]; part[i] = acc; acc += v; } }
    __syncthreads();
    int acc = part[t];
    for (int i = 0; i < 36; i++) { offs[base + i] = acc; acc += max(Dv[base + i], 1); }
}

// -------- kNN select from top-cache: 3 slots/lane -------------------------
__global__ __launch_bounds__(256) void hg16_sel_top(const unsigned long long* topc,
                                                    const int* Dv, const int* offs,
                                                    int* indeg, unsigned int* pairs) {
    const int t = threadIdx.x;
    const int lane = t & 63;
    const int gw = blockIdx.x * HRPB + (t >> 6);   // global row
    const int b = gw / HN, p = gw % HN;
    const int kk = max(Dv[gw], 1);
    if (kk > HCAP) return;                         // handled by fallback
    unsigned long long pk[3];
    unsigned key[3];
    #pragma unroll
    for (int s = 0; s < 3; s++) {
        pk[s] = topc[(size_t)gw * HCAP + (s << 6) + lane];
        key[s] = (unsigned)(pk[s] >> 12);
    }
    unsigned T; int cntLess, take;
    hg16_kth<3>(key, kk, T, cntLess, take);
    const int base = offs[gw];
    int cl = 0;
    #pragma unroll
    for (int s = 0; s < 3; s++) cl += (key[s] < T) ? 1 : 0;
    int off, tot;
    hg16_scan64(cl, lane, off, tot);
    int w = 0;
    #pragma unroll
    for (int s = 0; s < 3; s++) {
        if (key[s] < T) {
            int m = (int)(pk[s] & 0xFFFu);
            atomicAdd(&indeg[b * HN + m], 1);
            pairs[base + off + w] =
                ((unsigned)b << 24) | ((unsigned)p << 12) | (unsigned)m;
            w++;
        }
    }
    int lastm = -1;
    for (int t2 = 0; t2 < take; t2++) {            // ties at T: ascending m
        int mc = 0x7FFFFFFF;
        #pragma unroll
        for (int s = 0; s < 3; s++) {
            int m = (int)(pk[s] & 0xFFFu);
            if (key[s] == T && m > lastm && m < mc) mc = m;
        }
        int mmin = mc;
        #pragma unroll
        for (int o = 32; o > 0; o >>= 1) {
            int ov = __shfl_xor(mmin, o);
            mmin = ov < mmin ? ov : mmin;
        }
        if (mc == mmin) {
            atomicAdd(&indeg[b * HN + mmin], 1);
            pairs[base + cntLess + t2] =
                ((unsigned)b << 24) | ((unsigned)p << 12) | (unsigned)mmin;
        }
        lastm = mmin;
    }
}

// -------- fallback: full recompute for rows with Dv > HCAP (early-exit) ---
__global__ __launch_bounds__(256) void hg16_sel_fullfb(const float* xT, const float* xsq,
                                                       const int* Dv, const int* offs,
                                                       int* indeg, unsigned int* pairs) {
    const int t = threadIdx.x;
    const int b = blockIdx.x / (HN / HRPB);
    const int n0 = (blockIdx.x % (HN / HRPB)) * HRPB;
    bool need = false;
    #pragma unroll
    for (int q = 0; q < HRPB; q++) need |= (Dv[b * HN + n0 + q] > HCAP);
    if (!need) return;                              // ~all blocks exit here

    __shared__ float d[HRPB][HN];
    __shared__ float xr[HRPB][HC];
    const int r = t >> 6;
    const int lane = t & 63;
    xr[r][lane] = xT[(b * HC + lane) * HN + n0 + r];
    __syncthreads();
    float xs[HRPB];
    #pragma unroll
    for (int q = 0; q < HRPB; q++) xs[q] = xsq[b * HN + n0 + q];
    for (int m = t; m < HN; m += 256) {
        float dot0 = 0.f, dot1 = 0.f, dot2 = 0.f, dot3 = 0.f;
        #pragma unroll 8
        for (int c = 0; c < HC; c++) {
            float xv = xT[(b * HC + c) * HN + m];
            dot0 += xr[0][c] * xv;
            dot1 += xr[1][c] * xv;
            dot2 += xr[2][c] * xv;
            dot3 += xr[3][c] * xv;
        }
        float xsm = xsq[b * HN + m];
        d[0][m] = xs[0] + xsm - 2.f * dot0;
        d[1][m] = xs[1] + xsm - 2.f * dot1;
        d[2][m] = xs[2] + xsm - 2.f * dot2;
        d[3][m] = xs[3] + xsm - 2.f * dot3;
    }
    __syncthreads();
    const int p = n0 + r;
    const int gw = b * HN + p;
    const int kk = max(Dv[gw], 1);
    if (kk <= HCAP) return;                        // this wave's row is fine
    unsigned int key[NSLOT];
    #pragma unroll
    for (int s = 0; s < NSLOT; s++) {
        float f = d[r][(s << 6) | lane];
        unsigned int ub = __float_as_uint(f);
        key[s] = ub ^ (((unsigned int)(((int)ub) >> 31)) | 0x80000000u);
    }
    unsigned T; int cntLess, take;
    hg16_kth<NSLOT>(key, kk, T, cntLess, take);
    const int base = offs[gw];
    int cl = 0;
    #pragma unroll
    for (int s = 0; s < NSLOT; s++) cl += (key[s] < T) ? 1 : 0;
    int off, tot;
    hg16_scan64(cl, lane, off, tot);
    int w = 0;
    #pragma unroll
    for (int s = 0; s < NSLOT; s++) {
        if (key[s] < T) {
            int m = (s << 6) | lane;
            atomicAdd(&indeg[b * HN + m], 1);
            pairs[base + off + w] =
                ((unsigned)b << 24) | ((unsigned)p << 12) | (unsigned)m;
            w++;
        }
    }
    int lastm = -1;
    for (int t2 = 0; t2 < take; t2++) {
        int mc = 0x7FFFFFFF;
        #pragma unroll
        for (int s = 0; s < NSLOT; s++) {
            int m = (s << 6) | lane;
            if (key[s] == T && m > lastm && m < mc) mc = m;
        }
        int mmin = mc;
        #pragma unroll
        for (int o = 32; o > 0; o >>= 1) {
            int ov = __shfl_xor(mmin, o);
            mmin = ov < mmin ? ov : mmin;
        }
        if (mc == mmin) {
            atomicAdd(&indeg[b * HN + mmin], 1);
            pairs[base + cntLess + t2] =
                ((unsigned)b << 24) | ((unsigned)p << 12) | (unsigned)mmin;
        }
        lastm = mmin;
    }
}

__device__ __forceinline__ int hg16_lo(int rc) { return max(0, (rc - 3) / 2); }
__device__ __forceinline__ int hg16_hi(int rc) { return min(HW - 1, rc / 2); }

// -------- fused prep: h1 *= Dv^-1/2 ; z = 0 ; h2 = 0 ----------------------
__global__ __launch_bounds__(256) void hg16_prep(float* h1, const int* indeg,
                                                 float* z, float* h2) {
    int i = blockIdx.x * 256 + threadIdx.x;      // over B*N*C
    int node = i >> 6;
    int n = node % HN;
    int r = n / HL, c = n % HL;
    int cover = max(0, hg16_hi(r) - hg16_lo(r) + 1) * max(0, hg16_hi(c) - hg16_lo(c) + 1);
    int dvn = max(indeg[node] + cover, 1);
    h1[i] *= rsqrtf((float)dvn);
    int b = i / (HN * HC), rem = i % (HN * HC);
    z[b * HE * HC + rem] = 0.f;                  // window part written by edge
    h2[i] = 0.f;
}

// -------- fused edge kernel: kNN scatter + window means -------------------
__global__ __launch_bounds__(256) void hg16_edge(const unsigned int* pairs, const int* Dv,
                                                 const float* y, float* z) {
    int wv = (blockIdx.x * 256 + threadIdx.x) >> 6;
    int lane = threadIdx.x & 63;
    if (wv < NPAIRS) {
        unsigned int pk = pairs[wv];
        int b = pk >> 24;
        if (b >= HB) return;                     // defensive (poison)
        int p = (pk >> 12) & 0xFFF, m = pk & 0xFFF;
        float invde = 1.f / (float)max(Dv[b * HN + p], 1);
        atomicAdd(&z[(b * HE + p) * HC + lane], y[(b * HN + m) * HC + lane] * invde);
    } else {
        int w2 = wv - NPAIRS;
        if (w2 >= HB * HE2) return;
        int b = w2 / HE2, w = w2 % HE2;
        int wr = w / HW, wc = w % HW;
        float acc = 0.f;
        #pragma unroll
        for (int i = 0; i < 5; i++)
            #pragma unroll
            for (int j = 0; j < 5; j++)
                acc += y[(b * HN + (wr * 2 + i) * HL + wc * 2 + j) * HC + lane];
        z[(b * HE + HN + w) * HC + lane] = acc * (1.f / 25.f);
    }
}

// -------- h2[m] += z[p] over the pair list (atomic) -----------------------
__global__ __launch_bounds__(256) void hg16_gscatter(const unsigned int* pairs,
                                                     const float* z, float* h2) {
    int idx = (blockIdx.x * 256 + threadIdx.x) >> 6;
    int lane = threadIdx.x & 63;
    if (idx >= NPAIRS) return;
    unsigned int pk = pairs[idx];
    int b = pk >> 24;
    if (b >= HB) return;                         // defensive (poison)
    int p = (pk >> 12) & 0xFFF, m = pk & 0xFFF;
    atomicAdd(&h2[(b * HN + m) * HC + lane], z[(b * HE + p) * HC + lane]);
}

// -------- add window contributions + final Dv^-1/2 scale ------------------
__global__ __launch_bounds__(256) void hg16_gfinish(const float* z, const int* indeg, float* h2) {
    int wave = (blockIdx.x * 256 + threadIdx.x) >> 6;  // one wave per (b, node)
    int lane = threadIdx.x & 63;
    int b = wave / HN, n = wave % HN;
    int g = b * HN + n;
    float acc = h2[g * HC + lane];
    int r = n / HL, c = n % HL;
    int rlo = hg16_lo(r), rhi = hg16_hi(r), clo = hg16_lo(c), chi = hg16_hi(c);
    for (int wr = rlo; wr <= rhi; wr++)
        for (int wc = clo; wc <= chi; wc++)
            acc += z[(b * HE + HN + wr * HW + wc) * HC + lane];
    int dvn = max(indeg[g] + max(0, rhi - rlo + 1) * max(0, chi - clo + 1), 1);
    h2[g * HC + lane] = acc * rsqrtf((float)dvn);
}

// -------- BN stats --------------------------------------------------------
__global__ __launch_bounds__(256) void hg16_bnstats(const float* h2, float* bnsum, float* bnss) {
    int t = threadIdx.x;
    int c = t & 63, rg = t >> 6;
    int row0 = blockIdx.x * 36;      // 256 blocks * 36 rows = 9216
    float s = 0.f, ss = 0.f;
    for (int r = rg; r < 36; r += 4) {
        float v = h2[(row0 + r) * HC + c];
        s += v; ss += v * v;
    }
    __shared__ float ls[256], lss[256];
    ls[t] = s; lss[t] = ss;
    __syncthreads();
    if (t < 64) {
        s  = ls[t]  + ls[t + 64]  + ls[t + 128]  + ls[t + 192];
        ss = lss[t] + lss[t + 64] + lss[t + 128] + lss[t + 192];
        atomicAdd(&bnsum[t], s);
        atomicAdd(&bnss[t], ss);
    }
}

// -------- BN + ReLU + residual --------------------------------------------
__global__ __launch_bounds__(256) void hg16_final(const float* h2, const float* x,
                                                  const float* gamma, const float* beta,
                                                  const float* bnsum, const float* bnss,
                                                  float* out) {
    int i = blockIdx.x * 256 + threadIdx.x;
    int c = i & 63;
    const float M = (float)(HB * HN);
    float mean = bnsum[c] / M;
    float var  = bnss[c] / M - mean * mean;
    float inv  = rsqrtf(var + 1e-5f);
    float h = gamma[c] * (h2[i] - mean) * inv + beta[c];
    out[i] = fmaxf(h, 0.f) + x[i];
}

extern "C" void kernel_launch(void* const* d_in, const int* in_sizes, int n_in,
                              void* d_out, int out_size, void* d_ws, size_t ws_size,
                              hipStream_t stream) {
    const float* x     = (const float*)d_in[0];
    const float* W     = (const float*)d_in[1];
    const float* bias  = (const float*)d_in[2];
    const float* gamma = (const float*)d_in[3];
    const float* beta  = (const float*)d_in[4];
    float* out = (float*)d_out;
    (void)in_sizes; (void)n_in;

    char* ws = (char*)d_ws;
    size_t off = 0;
    float*              xsq   = (float*)(ws + off);              off += (size_t)HB * HN * 4;
    float*              h1    = (float*)(ws + off);              off += (size_t)HB * HN * HC * 4;
    float*              h2    = (float*)(ws + off);              off += (size_t)HB * HN * HC * 4;
    int*                Dv    = (int*)(ws + off);                off += (size_t)HB * HN * 4;
    int*                indeg = (int*)(ws + off);                off += (size_t)HB * HN * 4;
    int*                offs  = (int*)(ws + off);                off += (size_t)HB * HN * 4;
    unsigned int*       pairs = (unsigned int*)(ws + off);       off += (size_t)NPAIRS * 4;
    float*              bnsum = (float*)(ws + off);              off += 256;
    float*              bnss  = (float*)(ws + off);              off += 256;
    unsigned long long* topc  = (unsigned long long*)(ws + off); off += (size_t)HB * HN * HCAP * 8;
    float*              xT    = (float*)(ws + off);              // z aliases xT
    float*              z     = (float*)(ws + off);
    off += (size_t)HB * HE * HC * 4;   // max(xT, z) = z

    if (ws_size < off) {
        hg16_sentinel<<<(out_size + 255) / 256, 256, 0, stream>>>(out, out_size);
        return;
    }

    const int EDGE_WAVES = NPAIRS + HB * HE2;    // 103312, divisible by 4

    hg16_init<<<(HB * HN + 255) / 256, 256, 0, stream>>>(Dv, indeg, bnsum, bnss);
    hg16_linear<<<HB * HN, 64, 0, stream>>>(x, W, bias, h1, xsq, xT);
    hg16_knn_count<<<HB * (HN / HRPB), 256, 0, stream>>>(xT, xsq, Dv, topc);
    hg16_scan<<<1, 256, 0, stream>>>(Dv, offs);
    hg16_sel_top<<<HB * (HN / HRPB), 256, 0, stream>>>(topc, Dv, offs, indeg, pairs);
    hg16_sel_fullfb<<<HB * (HN / HRPB), 256, 0, stream>>>(xT, xsq, Dv, offs, indeg, pairs);
    hg16_prep<<<(HB * HN * HC) / 256, 256, 0, stream>>>(h1, indeg, z, h2);
    hg16_edge<<<EDGE_WAVES / 4, 256, 0, stream>>>(pairs, Dv, h1, z);
    hg16_gscatter<<<(NPAIRS * 64) / 256, 256, 0, stream>>>(pairs, z, h2);
    hg16_gfinish<<<(HB * HN) / 4, 256, 0, stream>>>(z, indeg, h2);
    hg16_bnstats<<<256, 256, 0, stream>>>(h2, bnsum, bnss);
    hg16_final<<<(HB * HN * HC) / 256, 256, 0, stream>>>(h2, x, gamma, beta, bnsum, bnss, out);
}

// Round 17
// 385.545 us; speedup vs baseline: 1.2546x; 1.2546x over previous
//
#include <hip/hip_runtime.h>

// HGNN layer, v17 — fp32. Count = v14's fast form (vectorized distance +
// pop top-11) + free per-lane top-4 cache store (4 u64/lane, 18.9 MB).
// Select = 4-slot bisection with exact coverage ballot (any lane 4th-key
// <= T, or kk>256 -> flagged fallback row). B=4, N=2304, C=64.

#define HB    4
#define HN    2304
#define HC    64
#define HK    11             // K_NEIGS + 1
#define HL    48
#define HW    22             // windows per dim
#define HE2   484            // 22*22 local edges
#define HE    (HN + HE2)
#define HRPB  4              // rows per block == waves per block
#define NSLOT 36             // keys per lane (2304/64)
#define HCAP4 256            // cache entries per row (4 u64 per lane)
#define NPAIRS (HB * HK * HN)   // sum of Dv == 11*N per batch, exact

__global__ void hg17_sentinel(float* out, int n) {
    int i = blockIdx.x * 256 + threadIdx.x;
    if (i < n) out[i] = 12345.0f;
}

__global__ void hg17_init(int* Dv, int* indeg, int* needfb, float* bnsum, float* bnss) {
    int i = blockIdx.x * 256 + threadIdx.x;
    if (i < HB * HN) { Dv[i] = 0; indeg[i] = 0; needfb[i] = 0; }
    if (i < HC) { bnsum[i] = 0.f; bnss[i] = 0.f; }
}

// -------- linear h1 = x W^T + b, xsq, f32 transpose (4 rows/block) --------
__global__ __launch_bounds__(256) void hg17_linear(const float* x, const float* W,
                                                   const float* bias, float* h1,
                                                   float* xsq, float* xT) {
    int wv = threadIdx.x >> 6, lane = threadIdx.x & 63;
    int row = blockIdx.x * 4 + wv;   // 0..B*N-1
    __shared__ float xr[4][HC];
    float v = x[row * HC + lane];
    xr[wv][lane] = v;
    __syncthreads();
    float sq = v * v;
    #pragma unroll
    for (int o = 32; o > 0; o >>= 1) sq += __shfl_xor(sq, o);
    if (lane == 0) xsq[row] = sq;
    int b = row / HN, n = row % HN;
    xT[(b * HC + lane) * HN + n] = v;
    float acc = bias[lane];
    #pragma unroll 8
    for (int c = 0; c < HC; c++) acc += xr[wv][c] * W[lane * HC + c];
    h1[row * HC + lane] = acc;
}

// ======== pop machinery (v12-proven): fixed kk=11 in count ================
__device__ __forceinline__ unsigned hg17_wave_min_u32(unsigned v) {
    #pragma unroll
    for (int o = 32; o > 0; o >>= 1) {
        unsigned ov = __shfl_xor(v, o);
        v = ov < v ? ov : v;
    }
    return v;
}

#define HG17_INS4(q0, q1, q2, q3, x)                                     \
    {                                                                    \
        unsigned long long x_ = (x), n_;                                 \
        n_ = q0 < x_ ? q0 : x_; x_ = q0 < x_ ? x_ : q0; q0 = n_;         \
        n_ = q1 < x_ ? q1 : x_; x_ = q1 < x_ ? x_ : q1; q1 = n_;         \
        n_ = q2 < x_ ? q2 : x_; x_ = q2 < x_ ? x_ : q2; q2 = n_;         \
        if (x_ < q3) q3 = x_;                                            \
    }

#define HG17_CE(u, v)                                                    \
    { unsigned long long t_ = u < v ? u : v; v = u < v ? v : u; u = t_; }

#define HG17_BUILD()                                                               \
    {                                                                              \
        unsigned long long a0 = CINF, a1 = CINF, a2 = CINF, a3 = CINF;             \
        unsigned long long b0 = CINF, b1 = CINF, b2 = CINF, b3 = CINF;             \
        _Pragma("unroll")                                                          \
        for (int s = 0; s < NSLOT / 2; s++) {                                      \
            unsigned long long pa = ((unsigned long long)key[s] << 12) |           \
                                    (unsigned)((s << 6) | lane);                   \
            unsigned long long pb = ((unsigned long long)key[s + 18] << 12) |      \
                                    (unsigned)(((s + 18) << 6) | lane);            \
            HG17_INS4(a0, a1, a2, a3, pa);                                         \
            HG17_INS4(b0, b1, b2, b3, pb);                                         \
        }                                                                          \
        c0 = a0 < b3 ? a0 : b3; c1 = a1 < b2 ? a1 : b2;                            \
        c2 = a2 < b1 ? a2 : b1; c3 = a3 < b0 ? a3 : b0;                            \
        HG17_CE(c0, c2); HG17_CE(c1, c3); HG17_CE(c0, c1); HG17_CE(c2, c3);        \
    }

#define HG17_EXTRACT(kk, EMIT)                                                     \
    {                                                                              \
        for (int j = 0; j < (kk); j++) {                                           \
            unsigned hk = (unsigned)(c0 >> 12);                                    \
            unsigned mk = hg17_wave_min_u32(hk);                                   \
            unsigned long long bal = __ballot(hk == mk);                           \
            bool iswin;                                                            \
            if (__popcll(bal) == 1) {                                              \
                iswin = (hk == mk);                                                \
            } else {                                                               \
                unsigned mc = (hk == mk) ? (unsigned)(c0 & 0xFFFu) : 0xFFFFFFFFu;  \
                unsigned mm = hg17_wave_min_u32(mc);                               \
                iswin = (mc == mm);                                                \
            }                                                                      \
            if (iswin) {                                                           \
                int bi = (int)(c0 & 0xFFFu);                                       \
                EMIT;                                                              \
                unsigned long long popped = c0;                                    \
                c0 = c1; c1 = c2; c2 = c3; c3 = CINF;                              \
                if (c0 == CINF) {                                                  \
                    _Pragma("unroll")                                              \
                    for (int s = 0; s < NSLOT; s++) {                              \
                        unsigned long long pk =                                    \
                            ((unsigned long long)key[s] << 12) |                   \
                            (unsigned)((s << 6) | lane);                           \
                        if (pk > popped) HG17_INS4(c0, c1, c2, c3, pk);            \
                    }                                                              \
                }                                                                  \
            }                                                                      \
        }                                                                          \
    }

// ======== bisection machinery (v13-proven), templated on slot count =======
template <int NS>
__device__ __forceinline__ void hg17_kth(const unsigned (&key)[NS], int kk,
                                         unsigned& T, int& cntLess, int& take) {
    unsigned andv = 0xFFFFFFFFu, orv = 0u;
    #pragma unroll
    for (int s = 0; s < NS; s++) { andv &= key[s]; orv |= key[s]; }
    #pragma unroll
    for (int o = 32; o > 0; o >>= 1) {
        andv &= (unsigned)__shfl_xor((int)andv, o);
        orv  |= (unsigned)__shfl_xor((int)orv, o);
    }
    unsigned diff = andv ^ orv;
    if (diff == 0u) { T = andv; cntLess = 0; take = kk; return; }
    int tstart = 31 - __builtin_clz(diff);
    unsigned lowmask = (tstart == 31) ? 0xFFFFFFFFu : ((1u << (tstart + 1)) - 1u);
    unsigned pref = andv & ~lowmask;
    int r = kk;
    for (int t = tstart; t >= 0; t--) {
        unsigned pt = pref >> t;
        int c = 0;
        #pragma unroll
        for (int s = 0; s < NS; s++) c += ((key[s] >> t) == pt) ? 1 : 0;
        #pragma unroll
        for (int o = 32; o > 0; o >>= 1) c += __shfl_xor(c, o);
        if (r > c) { r -= c; pref |= (1u << t); }
    }
    T = pref; cntLess = kk - r; take = r;
}

__device__ __forceinline__ void hg17_scan64(int v, int lane, int& excl, int& total) {
    int inc = v;
    #pragma unroll
    for (int o = 1; o < 64; o <<= 1) {
        int u = __shfl_up(inc, o);
        if (lane >= o) inc += u;
    }
    excl = inc - v;
    total = __shfl(inc, 63);
}

// -------- kNN count: vec distance + pop top-11 + free top-4 cache store ---
__global__ __launch_bounds__(256) void hg17_knn_count(const float* xT, const float* xsq,
                                                      int* Dv, unsigned long long* topc) {
    __shared__ float d[HRPB][HN];                // 36 KB
    __shared__ __align__(16) float xrt[HC][HRPB];
    const int t = threadIdx.x;
    const int b = blockIdx.x / (HN / HRPB);
    const int n0 = (blockIdx.x % (HN / HRPB)) * HRPB;
    const int r = t >> 6;
    const int lane = t & 63;
    xrt[lane][r] = xT[(b * HC + lane) * HN + n0 + r];
    __syncthreads();
    float xs[HRPB];
    #pragma unroll
    for (int q = 0; q < HRPB; q++) xs[q] = xsq[b * HN + n0 + q];

    #pragma unroll
    for (int i = 0; i < 4; i++) {                // m = 0..2047, float2/thread
        const int m = 512 * i + 2 * t;
        float2 d0 = {0.f, 0.f}, d1 = {0.f, 0.f}, d2 = {0.f, 0.f}, d3 = {0.f, 0.f};
        #pragma unroll 8
        for (int c = 0; c < HC; c++) {
            float4 xq = *reinterpret_cast<const float4*>(&xrt[c][0]);
            float2 xv = *reinterpret_cast<const float2*>(&xT[(b * HC + c) * HN + m]);
            d0.x += xq.x * xv.x; d0.y += xq.x * xv.y;
            d1.x += xq.y * xv.x; d1.y += xq.y * xv.y;
            d2.x += xq.z * xv.x; d2.y += xq.z * xv.y;
            d3.x += xq.w * xv.x; d3.y += xq.w * xv.y;
        }
        float s0 = xsq[b * HN + m], s1 = xsq[b * HN + m + 1];
        *reinterpret_cast<float2*>(&d[0][m]) =
            make_float2(xs[0] + s0 - 2.f * d0.x, xs[0] + s1 - 2.f * d0.y);
        *reinterpret_cast<float2*>(&d[1][m]) =
            make_float2(xs[1] + s0 - 2.f * d1.x, xs[1] + s1 - 2.f * d1.y);
        *reinterpret_cast<float2*>(&d[2][m]) =
            make_float2(xs[2] + s0 - 2.f * d2.x, xs[2] + s1 - 2.f * d2.y);
        *reinterpret_cast<float2*>(&d[3][m]) =
            make_float2(xs[3] + s0 - 2.f * d3.x, xs[3] + s1 - 2.f * d3.y);
    }
    {                                            // scalar tail m = 2048 + t
        const int m = 2048 + t;
        float d0 = 0.f, d1 = 0.f, d2 = 0.f, d3 = 0.f;
        #pragma unroll 8
        for (int c = 0; c < HC; c++) {
            float4 xq = *reinterpret_cast<const float4*>(&xrt[c][0]);
            float xv = xT[(b * HC + c) * HN + m];
            d0 += xq.x * xv; d1 += xq.y * xv; d2 += xq.z * xv; d3 += xq.w * xv;
        }
        float sm = xsq[b * HN + m];
        d[0][m] = xs[0] + sm - 2.f * d0;
        d[1][m] = xs[1] + sm - 2.f * d1;
        d[2][m] = xs[2] + sm - 2.f * d2;
        d[3][m] = xs[3] + sm - 2.f * d3;
    }
    __syncthreads();

    const int p = n0 + r;
    const int gw = b * HN + p;
    const unsigned long long CINF = ~0ull;
    unsigned int key[NSLOT];
    unsigned long long c0, c1, c2, c3;
    #pragma unroll
    for (int s = 0; s < NSLOT; s++) {
        float f = d[r][(s << 6) | lane];
        unsigned int ub = __float_as_uint(f);
        key[s] = ub ^ (((unsigned int)(((int)ub) >> 31)) | 0x80000000u);
    }
    HG17_BUILD();
    // free cache: per-lane sorted top-4 (save before EXTRACT mutates)
    {
        unsigned long long* tb = topc + (size_t)gw * HCAP4;
        tb[lane]       = c0;
        tb[64 + lane]  = c1;
        tb[128 + lane] = c2;
        tb[192 + lane] = c3;
    }
    // Dv counting: pop the 11 smallest; Dv counts the popped NEIGHBOR bi
    HG17_EXTRACT(HK, atomicAdd(&Dv[b * HN + bi], 1));
}

// -------- exclusive scan of Dv (9216 = 256*36) into offs ------------------
__global__ __launch_bounds__(256) void hg17_scan(const int* Dv, int* offs) {
    __shared__ int part[256];
    int t = threadIdx.x;
    int base = t * 36;
    int s = 0;
    for (int i = 0; i < 36; i++) s += max(Dv[base + i], 1);
    part[t] = s;
    __syncthreads();
    if (t == 0) { int acc = 0; for (int i = 0; i < 256; i++) { int v = part[i]; part[i] = acc; acc += v; } }
    __syncthreads();
    int acc = part[t];
    for (int i = 0; i < 36; i++) { offs[base + i] = acc; acc += max(Dv[base + i], 1); }
}

// -------- kNN select from top-4 cache, with exact coverage ballot ---------
__global__ __launch_bounds__(256) void hg17_sel_top(const unsigned long long* topc,
                                                    const int* Dv, const int* offs,
                                                    int* needfb, int* indeg,
                                                    unsigned int* pairs) {
    const int t = threadIdx.x;
    const int lane = t & 63;
    const int gw = blockIdx.x * HRPB + (t >> 6);   // global row
    const int b = gw / HN, p = gw % HN;
    const int kk = max(Dv[gw], 1);
    unsigned long long pk[4];
    unsigned key[4];
    #pragma unroll
    for (int s = 0; s < 4; s++) {
        pk[s] = topc[(size_t)gw * HCAP4 + (s << 6) + lane];
        key[s] = (unsigned)(pk[s] >> 12);
    }
    if (kk > HCAP4) {                              // cannot cover: fallback
        if (lane == 0) needfb[gw] = 1;
        return;
    }
    unsigned T; int cntLess, take;
    hg17_kth<4>(key, kk, T, cntLess, take);
    // coverage: exact iff every lane's 4th-smallest key > T
    unsigned long long bad = __ballot(key[3] <= T);
    if (bad != 0ull) {
        if (lane == 0) needfb[gw] = 1;
        return;
    }
    const int base = offs[gw];
    int cl = 0;
    #pragma unroll
    for (int s = 0; s < 4; s++) cl += (key[s] < T) ? 1 : 0;
    int off, tot;
    hg17_scan64(cl, lane, off, tot);
    int w = 0;
    #pragma unroll
    for (int s = 0; s < 4; s++) {
        if (key[s] < T) {
            int m = (int)(pk[s] & 0xFFFu);
            atomicAdd(&indeg[b * HN + m], 1);
            pairs[base + off + w] =
                ((unsigned)b << 24) | ((unsigned)p << 12) | (unsigned)m;
            w++;
        }
    }
    int lastm = -1;
    for (int t2 = 0; t2 < take; t2++) {            // ties at T: ascending m
        int mc = 0x7FFFFFFF;
        #pragma unroll
        for (int s = 0; s < 4; s++) {
            int m = (int)(pk[s] & 0xFFFu);
            if (key[s] == T && m > lastm && m < mc) mc = m;
        }
        int mmin = mc;
        #pragma unroll
        for (int o = 32; o > 0; o >>= 1) {
            int ov = __shfl_xor(mmin, o);
            mmin = ov < mmin ? ov : mmin;
        }
        if (mc == mmin) {
            atomicAdd(&indeg[b * HN + mmin], 1);
            pairs[base + cntLess + t2] =
                ((unsigned)b << 24) | ((unsigned)p << 12) | (unsigned)mmin;
        }
        lastm = mmin;
    }
}

// -------- fallback: full recompute for flagged rows (early-exit) ----------
__global__ __launch_bounds__(256) void hg17_sel_fullfb(const float* xT, const float* xsq,
                                                       const int* Dv, const int* offs,
                                                       const int* needfb, int* indeg,
                                                       unsigned int* pairs) {
    const int t = threadIdx.x;
    const int b = blockIdx.x / (HN / HRPB);
    const int n0 = (blockIdx.x % (HN / HRPB)) * HRPB;
    bool need = false;
    #pragma unroll
    for (int q = 0; q < HRPB; q++) need |= (needfb[b * HN + n0 + q] != 0);
    if (!need) return;                              // ~all blocks exit here

    __shared__ float d[HRPB][HN];
    __shared__ float xr[HRPB][HC];
    const int r = t >> 6;
    const int lane = t & 63;
    xr[r][lane] = xT[(b * HC + lane) * HN + n0 + r];
    __syncthreads();
    float xs[HRPB];
    #pragma unroll
    for (int q = 0; q < HRPB; q++) xs[q] = xsq[b * HN + n0 + q];
    for (int m = t; m < HN; m += 256) {
        float dot0 = 0.f, dot1 = 0.f, dot2 = 0.f, dot3 = 0.f;
        #pragma unroll 8
        for (int c = 0; c < HC; c++) {
            float xv = xT[(b * HC + c) * HN + m];
            dot0 += xr[0][c] * xv;
            dot1 += xr[1][c] * xv;
            dot2 += xr[2][c] * xv;
            dot3 += xr[3][c] * xv;
        }
        float xsm = xsq[b * HN + m];
        d[0][m] = xs[0] + xsm - 2.f * dot0;
        d[1][m] = xs[1] + xsm - 2.f * dot1;
        d[2][m] = xs[2] + xsm - 2.f * dot2;
        d[3][m] = xs[3] + xsm - 2.f * dot3;
    }
    __syncthreads();
    const int p = n0 + r;
    const int gw = b * HN + p;
    if (needfb[gw] == 0) return;                   // this wave's row is fine
    const int kk = max(Dv[gw], 1);
    unsigned int key[NSLOT];
    #pragma unroll
    for (int s = 0; s < NSLOT; s++) {
        float f = d[r][(s << 6) | lane];
        unsigned int ub = __float_as_uint(f);
        key[s] = ub ^ (((unsigned int)(((int)ub) >> 31)) | 0x80000000u);
    }
    unsigned T; int cntLess, take;
    hg17_kth<NSLOT>(key, kk, T, cntLess, take);
    const int base = offs[gw];
    int cl = 0;
    #pragma unroll
    for (int s = 0; s < NSLOT; s++) cl += (key[s] < T) ? 1 : 0;
    int off, tot;
    hg17_scan64(cl, lane, off, tot);
    int w = 0;
    #pragma unroll
    for (int s = 0; s < NSLOT; s++) {
        if (key[s] < T) {
            int m = (s << 6) | lane;
            atomicAdd(&indeg[b * HN + m], 1);
            pairs[base + off + w] =
                ((unsigned)b << 24) | ((unsigned)p << 12) | (unsigned)m;
            w++;
        }
    }
    int lastm = -1;
    for (int t2 = 0; t2 < take; t2++) {
        int mc = 0x7FFFFFFF;
        #pragma unroll
        for (int s = 0; s < NSLOT; s++) {
            int m = (s << 6) | lane;
            if (key[s] == T && m > lastm && m < mc) mc = m;
        }
        int mmin = mc;
        #pragma unroll
        for (int o = 32; o > 0; o >>= 1) {
            int ov = __shfl_xor(mmin, o);
            mmin = ov < mmin ? ov : mmin;
        }
        if (mc == mmin) {
            atomicAdd(&indeg[b * HN + mmin], 1);
            pairs[base + cntLess + t2] =
                ((unsigned)b << 24) | ((unsigned)p << 12) | (unsigned)mmin;
        }
        lastm = mmin;
    }
}

__device__ __forceinline__ int hg17_lo(int rc) { return max(0, (rc - 3) / 2); }
__device__ __forceinline__ int hg17_hi(int rc) { return min(HW - 1, rc / 2); }

// -------- fused prep: h1 *= Dv^-1/2 ; z = 0 ; h2 = 0 ----------------------
__global__ __launch_bounds__(256) void hg17_prep(float* h1, const int* indeg,
                                                 float* z, float* h2) {
    int i = blockIdx.x * 256 + threadIdx.x;      // over B*N*C
    int node = i >> 6;
    int n = node % HN;
    int r = n / HL, c = n % HL;
    int cover = max(0, hg17_hi(r) - hg17_lo(r) + 1) * max(0, hg17_hi(c) - hg17_lo(c) + 1);
    int dvn = max(indeg[node] + cover, 1);
    h1[i] *= rsqrtf((float)dvn);
    int b = i / (HN * HC), rem = i % (HN * HC);
    z[b * HE * HC + rem] = 0.f;                  // window part written by edge
    h2[i] = 0.f;
}

// -------- fused edge kernel: kNN scatter + window means -------------------
__global__ __launch_bounds__(256) void hg17_edge(const unsigned int* pairs, const int* Dv,
                                                 const float* y, float* z) {
    int wv = (blockIdx.x * 256 + threadIdx.x) >> 6;
    int lane = threadIdx.x & 63;
    if (wv < NPAIRS) {
        unsigned int pk = pairs[wv];
        int b = pk >> 24;
        if (b >= HB) return;                     // defensive (poison)
        int p = (pk >> 12) & 0xFFF, m = pk & 0xFFF;
        float invde = 1.f / (float)max(Dv[b * HN + p], 1);
        atomicAdd(&z[(b * HE + p) * HC + lane], y[(b * HN + m) * HC + lane] * invde);
    } else {
        int w2 = wv - NPAIRS;
        if (w2 >= HB * HE2) return;
        int b = w2 / HE2, w = w2 % HE2;
        int wr = w / HW, wc = w % HW;
        float acc = 0.f;
        #pragma unroll
        for (int i = 0; i < 5; i++)
            #pragma unroll
            for (int j = 0; j < 5; j++)
                acc += y[(b * HN + (wr * 2 + i) * HL + wc * 2 + j) * HC + lane];
        z[(b * HE + HN + w) * HC + lane] = acc * (1.f / 25.f);
    }
}

// -------- h2[m] += z[p] over the pair list (atomic) -----------------------
__global__ __launch_bounds__(256) void hg17_gscatter(const unsigned int* pairs,
                                                     const float* z, float* h2) {
    int idx = (blockIdx.x * 256 + threadIdx.x) >> 6;
    int lane = threadIdx.x & 63;
    if (idx >= NPAIRS) return;
    unsigned int pk = pairs[idx];
    int b = pk >> 24;
    if (b >= HB) return;                         // defensive (poison)
    int p = (pk >> 12) & 0xFFF, m = pk & 0xFFF;
    atomicAdd(&h2[(b * HN + m) * HC + lane], z[(b * HE + p) * HC + lane]);
}

// -------- add window contributions + final Dv^-1/2 scale ------------------
__global__ __launch_bounds__(256) void hg17_gfinish(const float* z, const int* indeg, float* h2) {
    int wave = (blockIdx.x * 256 + threadIdx.x) >> 6;  // one wave per (b, node)
    int lane = threadIdx.x & 63;
    int b = wave / HN, n = wave % HN;
    int g = b * HN + n;
    float acc = h2[g * HC + lane];
    int r = n / HL, c = n % HL;
    int rlo = hg17_lo(r), rhi = hg17_hi(r), clo = hg17_lo(c), chi = hg17_hi(c);
    for (int wr = rlo; wr <= rhi; wr++)
        for (int wc = clo; wc <= chi; wc++)
            acc += z[(b * HE + HN + wr * HW + wc) * HC + lane];
    int dvn = max(indeg[g] + max(0, rhi - rlo + 1) * max(0, chi - clo + 1), 1);
    h2[g * HC + lane] = acc * rsqrtf((float)dvn);
}

// -------- BN stats --------------------------------------------------------
__global__ __launch_bounds__(256) void hg17_bnstats(const float* h2, float* bnsum, float* bnss) {
    int t = threadIdx.x;
    int c = t & 63, rg = t >> 6;
    int row0 = blockIdx.x * 36;      // 256 blocks * 36 rows = 9216
    float s = 0.f, ss = 0.f;
    for (int r = rg; r < 36; r += 4) {
        float v = h2[(row0 + r) * HC + c];
        s += v; ss += v * v;
    }
    __shared__ float ls[256], lss[256];
    ls[t] = s; lss[t] = ss;
    __syncthreads();
    if (t < 64) {
        s  = ls[t]  + ls[t + 64]  + ls[t + 128]  + ls[t + 192];
        ss = lss[t] + lss[t + 64] + lss[t + 128] + lss[t + 192];
        atomicAdd(&bnsum[t], s);
        atomicAdd(&bnss[t], ss);
    }
}

// -------- BN + ReLU + residual --------------------------------------------
__global__ __launch_bounds__(256) void hg17_final(const float* h2, const float* x,
                                                  const float* gamma, const float* beta,
                                                  const float* bnsum, const float* bnss,
                                                  float* out) {
    int i = blockIdx.x * 256 + threadIdx.x;
    int c = i & 63;
    const float M = (float)(HB * HN);
    float mean = bnsum[c] / M;
    float var  = bnss[c] / M - mean * mean;
    float inv  = rsqrtf(var + 1e-5f);
    float h = gamma[c] * (h2[i] - mean) * inv + beta[c];
    out[i] = fmaxf(h, 0.f) + x[i];
}

extern "C" void kernel_launch(void* const* d_in, const int* in_sizes, int n_in,
                              void* d_out, int out_size, void* d_ws, size_t ws_size,
                              hipStream_t stream) {
    const float* x     = (const float*)d_in[0];
    const float* W     = (const float*)d_in[1];
    const float* bias  = (const float*)d_in[2];
    const float* gamma = (const float*)d_in[3];
    const float* beta  = (const float*)d_in[4];
    float* out = (float*)d_out;
    (void)in_sizes; (void)n_in;

    char* ws = (char*)d_ws;
    size_t off = 0;
    float*              xsq    = (float*)(ws + off);              off += (size_t)HB * HN * 4;
    float*              h1     = (float*)(ws + off);              off += (size_t)HB * HN * HC * 4;
    float*              h2     = (float*)(ws + off);              off += (size_t)HB * HN * HC * 4;
    int*                Dv     = (int*)(ws + off);                off += (size_t)HB * HN * 4;
    int*                indeg  = (int*)(ws + off);                off += (size_t)HB * HN * 4;
    int*                offs   = (int*)(ws + off);                off += (size_t)HB * HN * 4;
    int*                needfb = (int*)(ws + off);                off += (size_t)HB * HN * 4;
    unsigned int*       pairs  = (unsigned int*)(ws + off);       off += (size_t)NPAIRS * 4;
    float*              bnsum  = (float*)(ws + off);              off += 256;
    float*              bnss   = (float*)(ws + off);              off += 256;
    unsigned long long* topc   = (unsigned long long*)(ws + off); off += (size_t)HB * HN * HCAP4 * 8;
    float*              xT     = (float*)(ws + off);              // z aliases xT
    float*              z      = (float*)(ws + off);
    off += (size_t)HB * HE * HC * 4;   // max(xT, z) = z

    if (ws_size < off) {
        hg17_sentinel<<<(out_size + 255) / 256, 256, 0, stream>>>(out, out_size);
        return;
    }

    const int EDGE_WAVES = NPAIRS + HB * HE2;    // 103312, divisible by 4

    hg17_init<<<(HB * HN + 255) / 256, 256, 0, stream>>>(Dv, indeg, needfb, bnsum, bnss);
    hg17_linear<<<HB * HN / 4, 256, 0, stream>>>(x, W, bias, h1, xsq, xT);
    hg17_knn_count<<<HB * (HN / HRPB), 256, 0, stream>>>(xT, xsq, Dv, topc);
    hg17_scan<<<1, 256, 0, stream>>>(Dv, offs);
    hg17_sel_top<<<HB * (HN / HRPB), 256, 0, stream>>>(topc, Dv, offs, needfb, indeg, pairs);
    hg17_sel_fullfb<<<HB * (HN / HRPB), 256, 0, stream>>>(xT, xsq, Dv, offs, needfb, indeg, pairs);
    hg17_prep<<<(HB * HN * HC) / 256, 256, 0, stream>>>(h1, indeg, z, h2);
    hg17_edge<<<EDGE_WAVES / 4, 256, 0, stream>>>(pairs, Dv, h1, z);
    hg17_gscatter<<<(NPAIRS * 64) / 256, 256, 0, stream>>>(pairs, z, h2);
    hg17_gfinish<<<(HB * HN) / 4, 256, 0, stream>>>(z, indeg, h2);
    hg17_bnstats<<<256, 256, 0, stream>>>(h2, bnsum, bnss);
    hg17_final<<<(HB * HN * HC) / 256, 256, 0, stream>>>(h2, x, gamma, beta, bnsum, bnss, out);
}